// Round 29
// baseline (288.283 us; speedup 1.0000x reference)
//
#include <hip/hip_runtime.h>
#include <hip/hip_fp16.h>
#include <math.h>

#define NN 100000
#define EE 1600000
#define IND 256
#define SLOPE 0.2f

#define BUKBITS 9
#define BUKSZ 512            // nodes per bucket
#define NBUK 196             // ceil(NN/512)
#define CAP 8960             // bucket capacity: mean 8192 + 8*sigma(90)
#define CHUNK 4096           // edges per bin block
#define BINBLK 391           // ceil(EE/CHUNK)
#define NODEBLK 391          // ceil(NN/256)
#define SKB3 256             // semantic_key v7 blocks per m-slice
#define SKTILES 6250         // NN/16 exactly
#define FCB (2 * NODEBLK)    // 782 fc-role blocks
#define FUSEGRID (FCB + 4 * BINBLK + 1)   // 2347: fc + bin + prep_V roles
#define FUSESMEM 22832       // bin role's LDS need (max of roles)

typedef float f4 __attribute__((ext_vector_type(4)));     // native vec for nt builtins
typedef _Float16 h2 __attribute__((ext_vector_type(2)));  // packed fp16 pair
typedef _Float16 h8 __attribute__((ext_vector_type(8)));  // MFMA A/B fragment
typedef float fx4 __attribute__((ext_vector_type(4)));    // MFMA C/D fragment

// ---------------------------------------------------------------------------
// fp16 row unpack: 16B raw -> 8 floats
// ---------------------------------------------------------------------------
__device__ __forceinline__ void unpack8(const f4& raw, float* hs) {
  union { f4 v; __half2 p[4]; } u;
  u.v = raw;
#pragma unroll
  for (int j = 0; j < 4; ++j) {
    float2 f = __half22float2(u.p[j]);
    hs[2 * j] = f.x;
    hs[2 * j + 1] = f.y;
  }
}

// ---------------------------------------------------------------------------
// FUSED fc + bin + prep_V (r28 structure + r29 role INTERLEAVE).
// r28 assigned roles by contiguous index ranges: all 782 fc blocks dispatched
// first, saturating CUs -> roles ran mostly serially INSIDE the kernel
// (128us vs the ~105 overlap target). Fix: interleave 1:2 by blockIdx%3
// (fc:bin = 782:1564) so fc (stream/VALU-bound) and bin (LDS-atomic-bound)
// are co-resident on every CU from the start.
//   blockIdx%3==0, idx/3<FCB : fc role (bid = idx/3)
//   blockIdx%3==0, idx/3==FCB: prep_V role (block 2346)
//   blockIdx%3!=0            : bin role (binid = (idx/3)*2 + idx%3 - 1)
// ---------------------------------------------------------------------------
__global__ __launch_bounds__(256) void fc_bin_kernel(
    const float* __restrict__ xa, const float* __restrict__ xp,
    const float* __restrict__ Wa, const float* __restrict__ ba,
    const float* __restrict__ Wp, const float* __restrict__ bp,
    f4* __restrict__ h16,
    const int* __restrict__ e0, const int* __restrict__ e1,
    const int* __restrict__ e2, const int* __restrict__ e3,
    int* __restrict__ gcur, int* __restrict__ edge_src,
    const float* __restrict__ gWs, const float* __restrict__ gas,
    const float* __restrict__ gWd, const float* __restrict__ gad,
    float* __restrict__ Vs, float* __restrict__ Vd) {
  extern __shared__ char smem[];
  int t = threadIdx.x;
  int third = blockIdx.x / 3;
  int rem = blockIdx.x - third * 3;
  if (rem == 0 && third < FCB) {
    // ======================= fc role (r18, frozen) =======================
    float* sW = (float*)smem;          // 8 KB
    float* sB = sW + IND * 8;          // 32 B
    int bid = third;
    int type = bid >= NODEBLK;
    int lrow = (type ? bid - NODEBLK : bid) * 256 + t;
    const float* W = type ? Wp : Wa;
    const float* bb = type ? bp : ba;
    for (int i = t; i < IND * 8; i += 256) sW[i] = W[i];
    if (t < 8) sB[t] = bb[t];
    __syncthreads();
    if (lrow >= NN) return;
    const float* x = (type ? xp : xa) + (size_t)lrow * IND;
    float acc[8];
#pragma unroll
    for (int c = 0; c < 8; ++c) acc[c] = sB[c];
#pragma unroll 4
    for (int k4 = 0; k4 < IND / 4; ++k4) {
      float4 xv = ((const float4*)x)[k4];
      float xk[4] = {xv.x, xv.y, xv.z, xv.w};
#pragma unroll
      for (int kk = 0; kk < 4; ++kk) {
        const float* wr = &sW[(k4 * 4 + kk) * 8];
#pragma unroll
        for (int c = 0; c < 8; ++c) acc[c] = fmaf(xk[kk], wr[c], acc[c]);
      }
    }
    union { f4 v; __half2 p[4]; } u;
#pragma unroll
    for (int c = 0; c < 4; ++c)
      u.p[c] = __floats2half2_rn(acc[2 * c], acc[2 * c + 1]);
    h16[(size_t)type * NN + lrow] = u.v;
  } else if (rem != 0) {
    // ============================ bin role ==============================
    int b = third * 2 + rem - 1;       // 0..1563
    int et = b / BINBLK;
    int chunk = b - et * BINBLK;
    int* s_pack = (int*)smem;                               // 16 KB
    unsigned char* s_buk = (unsigned char*)(s_pack + CHUNK); // 4 KB
    int* s_hist = (int*)(s_buk + CHUNK);                    // 784 B
    int* s_base = s_hist + NBUK;                            // 784 B
    int* s_cur = s_base + NBUK;                             // 784 B
    const int* ei = et == 0 ? e0 : et == 1 ? e1 : et == 2 ? e2 : e3;
    for (int bb = t; bb < NBUK; bb += 256) { s_hist[bb] = 0; s_cur[bb] = 0; }
    __syncthreads();
    int base = chunk * CHUNK;
#pragma unroll
    for (int r = 0; r < CHUNK / 256; ++r) {
      int i = r * 256 + t;
      int e = base + i;
      int bk = 255;
      if (e < EE) {
        int s = __builtin_nontemporal_load(ei + e);
        int d = __builtin_nontemporal_load(ei + EE + e);
        s_pack[i] = s | ((d & (BUKSZ - 1)) << 17);
        bk = d >> BUKBITS;
        atomicAdd(&s_hist[bk], 1);
      }
      s_buk[i] = (unsigned char)bk;
    }
    __syncthreads();
    for (int bb = t; bb < NBUK; bb += 256)
      s_base[bb] = atomicAdd(&gcur[et * NBUK + bb], s_hist[bb]);
    __syncthreads();
#pragma unroll
    for (int r = 0; r < CHUNK / 256; ++r) {
      int i = r * 256 + t;
      int bk = s_buk[i];
      if (bk != 255) {
        int pos = s_base[bk] + atomicAdd(&s_cur[bk], 1);
        if (pos < CAP)  // statistically impossible overflow guard
          edge_src[(size_t)(et * NBUK + bk) * CAP + pos] = s_pack[i];
      }
    }
  } else {
    // =========================== prep_V role ============================
    int et = t >> 6, k = (t >> 3) & 7, hh = t & 7;
    float accS = 0.f, accD = 0.f;
#pragma unroll
    for (int c = 0; c < 8; ++c) {
      accS += gWs[et * 512 + k * 64 + hh * 8 + c] * gas[et * 64 + hh * 8 + c];
      accD += gWd[et * 512 + k * 64 + hh * 8 + c] * gad[et * 64 + hh * 8 + c];
    }
    Vs[et * 64 + k * 8 + hh] = accS;
    Vd[et * 64 + k * 8 + hh] = accD;
  }
}

// ---------------------------------------------------------------------------
// Phase 2: per-bucket CSR (256 threads).
// ---------------------------------------------------------------------------
__global__ __launch_bounds__(256) void csr_kernel(
    const int* __restrict__ gcur, int* __restrict__ edge_src,
    int* __restrict__ counts, int* __restrict__ rowptr) {
  __shared__ int s_data[CAP];
  __shared__ int s_hist[BUKSZ], s_off[BUKSZ], s_part[256];
  int buk = blockIdx.x, et = blockIdx.y, t = threadIdx.x;
  int bsz = gcur[et * NBUK + buk];
  if (bsz > CAP) bsz = CAP;
  int ebase = (et * NBUK + buk) * CAP;
  for (int j = t; j < BUKSZ; j += 256) s_hist[j] = 0;
  __syncthreads();
  for (int i = t; i < bsz; i += 256) {
    int v = __builtin_nontemporal_load(edge_src + ebase + i);
    s_data[i] = v;
    atomicAdd(&s_hist[v >> 17], 1);
  }
  __syncthreads();
  int b2 = t * 2;
  int a0 = s_hist[b2], a1 = s_hist[b2 + 1];
  int tot = a0 + a1;
  s_part[t] = tot;
  __syncthreads();
#pragma unroll
  for (int off = 1; off < 256; off <<= 1) {
    int v = (t >= off) ? s_part[t - off] : 0;
    __syncthreads();
    s_part[t] += v;
    __syncthreads();
  }
  int ex = s_part[t] - tot;
  s_off[b2] = ex;
  s_off[b2 + 1] = ex + a0;
  __syncthreads();
  for (int j = t; j < BUKSZ; j += 256) {
    int node = buk * BUKSZ + j;
    if (node < NN) {
      counts[(size_t)et * NN + node] = s_hist[j];
      rowptr[(size_t)et * NN + node] = ebase + s_off[j];
    }
  }
  __syncthreads();
  for (int i = t; i < bsz; i += 256) {
    int v = s_data[i];
    int pos = atomicAdd(&s_off[v >> 17], 1);
    edge_src[ebase + pos] = v & 0x1FFFF;
  }
}

// ---------------------------------------------------------------------------
// GAT pull edge step (fp16 src row).
// ---------------------------------------------------------------------------
__device__ __forceinline__ void gat_edge16(
    const f4& raw, const float* __restrict__ Vse,
    const float ad[8], float g[64], float z[8]) {
  float hs[8];
  unpack8(raw, hs);
#pragma unroll
  for (int hh = 0; hh < 8; ++hh) {
    float e = ad[hh];
#pragma unroll
    for (int k = 0; k < 8; ++k) e = fmaf(hs[k], Vse[k * 8 + hh], e);
    e = e > 0.f ? e : SLOPE * e;
    float w = __expf(e);
    z[hh] += w;
#pragma unroll
    for (int k = 0; k < 8; ++k) g[hh * 8 + k] = fmaf(w, hs[k], g[hh * 8 + k]);
  }
}

// ---------------------------------------------------------------------------
// GAT pull: thread-per-node, fp16 h (1 gather/edge), 4-edge batches,
// fp16 out_et epilogue. Validated L2-request-rate floor (~95us).
// ---------------------------------------------------------------------------
__global__ __launch_bounds__(256) void gat_pull(
    const f4* __restrict__ h16,
    const int* __restrict__ rowptr, const int* __restrict__ counts,
    const int* __restrict__ edge_src,
    const float* __restrict__ Wsrc_all, const float* __restrict__ Vs,
    const float* __restrict__ Vd,
    const float* __restrict__ bias_all, f4* __restrict__ out16) {
  int b = blockIdx.x;
  int xcd = b & 7;
  int g_ = xcd >> 2;                      // src type this XCD owns
  int sid = (b >> 3) * 4 + (xcd & 3);     // 0..783
  if (sid >= 2 * NODEBLK) return;
  int et = (sid < NODEBLK) ? g_ : g_ + 2; // a:{0,2}  p:{1,3}
  int nb = (sid < NODEBLK) ? sid : sid - NODEBLK;
  int n = nb * 256 + threadIdx.x;
  if (n >= NN) return;
  int st = et & 1;                           // src type: 0=a,1=p
  int dt = (et & 1) ^ (et < 2 ? 1 : 0);      // dst type
  const f4* hsrc = h16 + (size_t)st * NN;
  const f4* hdst = h16 + (size_t)dt * NN;
  const float* Ws = Wsrc_all + et * 512;
  const float* Vse = Vs + et * 64;
  const float* Vde = Vd + et * 64;
  const float* bs = bias_all + et * 64;

  float hd[8];
  unpack8(hdst[n], hd);
  float ad[8];
#pragma unroll
  for (int hh = 0; hh < 8; ++hh) {
    float acc = 0.f;
#pragma unroll
    for (int k = 0; k < 8; ++k) acc = fmaf(hd[k], Vde[k * 8 + hh], acc);
    ad[hh] = acc;
  }
  float g[64];
  float z[8];
#pragma unroll
  for (int i = 0; i < 64; ++i) g[i] = 0.f;
#pragma unroll
  for (int hh = 0; hh < 8; ++hh) z[hh] = 0.f;

  int start = rowptr[(size_t)et * NN + n];
  int deg = counts[(size_t)et * NN + n];
  const int* es = edge_src + start;
  int i = 0;
#pragma unroll 1
  for (; i + 4 <= deg; i += 4) {
    int s0 = __builtin_nontemporal_load(es + i);
    int s1 = __builtin_nontemporal_load(es + i + 1);
    int s2 = __builtin_nontemporal_load(es + i + 2);
    int s3 = __builtin_nontemporal_load(es + i + 3);
    f4 r0 = hsrc[s0];
    f4 r1 = hsrc[s1];
    f4 r2 = hsrc[s2];
    f4 r3 = hsrc[s3];
    gat_edge16(r0, Vse, ad, g, z);
    gat_edge16(r1, Vse, ad, g, z);
    gat_edge16(r2, Vse, ad, g, z);
    gat_edge16(r3, Vse, ad, g, z);
  }
#pragma unroll 1
  for (; i < deg; ++i) {
    int s = __builtin_nontemporal_load(es + i);
    f4 r = hsrc[s];
    gat_edge16(r, Vse, ad, g, z);
  }

  f4* op = out16 + ((size_t)et * NN + n) * 8;   // 8 f4 chunks = 64 halves
#pragma unroll
  for (int hh = 0; hh < 8; ++hh) {
    float rz = 1.f / (z[hh] + 1e-16f);
    float o[8];
#pragma unroll
    for (int c = 0; c < 8; ++c) {
      float acc = 0.f;
#pragma unroll
      for (int k = 0; k < 8; ++k)
        acc = fmaf(g[hh * 8 + k], Ws[k * 64 + hh * 8 + c], acc);
      o[c] = acc * rz + bs[hh * 8 + c];
    }
    union { f4 v; __half2 p[4]; } u;
#pragma unroll
    for (int c = 0; c < 4; ++c)
      u.p[c] = __floats2half2_rn(o[2 * c], o[2 * c + 1]);
    op[hh] = u.v;
  }
}

// ---------------------------------------------------------------------------
// Semantic attention keys (v7, MFMA) — r24 verified.
// ---------------------------------------------------------------------------
__global__ __launch_bounds__(256) void semantic_key(
    const f4* __restrict__ out16, const float* __restrict__ Wk,
    const float* __restrict__ bk, float* __restrict__ key) {
  __shared__ float s_red[4][64];
  int m = blockIdx.y;
  int t = threadIdx.x;
  int lane = t & 63;
  int w = t >> 6;
  int kg = lane >> 4;      // k-group 0..3
  int col = lane & 15;
  h8 bfrag[2][4];
#pragma unroll
  for (int ks = 0; ks < 2; ++ks)
#pragma unroll
    for (int jt = 0; jt < 4; ++jt) {
      h8 bf;
#pragma unroll
      for (int i = 0; i < 8; ++i)
        bf[i] = (_Float16)Wk[(ks * 32 + kg * 8 + i) * 64 + jt * 16 + col];
      bfrag[ks][jt] = bf;
    }
  float bkv[4];
#pragma unroll
  for (int jt = 0; jt < 4; ++jt) bkv[jt] = bk[jt * 16 + col];
  float kacc[4] = {0.f, 0.f, 0.f, 0.f};
  const f4* base = out16 + (size_t)m * NN * 8;
  int gw = blockIdx.x * 4 + w;            // 0..1023
#pragma unroll 1
  for (int tile = gw; tile < SKTILES; tile += SKB3 * 4) {
    union { f4 v; h8 h; } a0u, a1u;
    const f4* rowp = base + (size_t)(tile * 16 + col) * 8;
    a0u.v = rowp[kg];
    a1u.v = rowp[4 + kg];
#pragma unroll
    for (int jt = 0; jt < 4; ++jt) {
      fx4 d = {0.f, 0.f, 0.f, 0.f};
      d = __builtin_amdgcn_mfma_f32_16x16x32_f16(a0u.h, bfrag[0][jt], d, 0, 0, 0);
      d = __builtin_amdgcn_mfma_f32_16x16x32_f16(a1u.h, bfrag[1][jt], d, 0, 0, 0);
#pragma unroll
      for (int r = 0; r < 4; ++r) {
        float x = d[r] + bkv[jt];
        kacc[jt] += 1.f - 2.f / (__expf(2.f * x) + 1.f);  // tanh
      }
    }
  }
#pragma unroll
  for (int jt = 0; jt < 4; ++jt) {
    kacc[jt] += __shfl_xor(kacc[jt], 16, 64);
    kacc[jt] += __shfl_xor(kacc[jt], 32, 64);
  }
  if (lane < 16) {
#pragma unroll
    for (int jt = 0; jt < 4; ++jt) s_red[w][jt * 16 + col] = kacc[jt];
  }
  __syncthreads();
  if (t < 64) {
    float v = s_red[0][t] + s_red[1][t] + s_red[2][t] + s_red[3][t];
    atomicAdd(&key[m * 64 + t], v);
  }
}

// ---------------------------------------------------------------------------
// Scores: softmax over each node-type's pair of edge types.
// ---------------------------------------------------------------------------
__global__ __launch_bounds__(64) void scores_k(
    const float* __restrict__ key, const float* __restrict__ q,
    float* __restrict__ wsc) {
  int l = threadIdx.x;
  float qv = q[l];
  float d[4];
#pragma unroll
  for (int m = 0; m < 4; ++m) {
    float p = qv * key[m * 64 + l];
#pragma unroll
    for (int off = 32; off; off >>= 1) p += __shfl_xor(p, off, 64);
    d[m] = p * (1.0f / NN);  // mean over nodes
  }
  if (l == 0) {
    {
      float mx = fmaxf(d[1], d[2]);
      float e1 = __expf(d[1] - mx), e2 = __expf(d[2] - mx);
      float inv = 1.f / (e1 + e2);
      wsc[1] = e1 * inv;
      wsc[2] = e2 * inv;
    }
    {
      float mx = fmaxf(d[0], d[3]);
      float e0 = __expf(d[0] - mx), e3 = __expf(d[3] - mx);
      float inv = 1.f / (e0 + e3);
      wsc[0] = e0 * inv;
      wsc[3] = e3 * inv;
    }
  }
}

// ---------------------------------------------------------------------------
// Combine (fp16 out_et): thread handles 8 outputs (16B fp16 per et half).
// ---------------------------------------------------------------------------
__global__ __launch_bounds__(256) void combine_kernel(
    const f4* __restrict__ out16, const float* __restrict__ wsc,
    float* __restrict__ out) {
  size_t i8 = (size_t)blockIdx.x * 256 + threadIdx.x;  // 8-float chunk over [2][N][8]
  if (i8 >= (size_t)2 * NN * 8) return;
  int type = i8 >= (size_t)NN * 8;
  size_t r8 = type ? i8 - (size_t)NN * 8 : i8;
  int m0 = type ? 0 : 1;
  int m1 = type ? 3 : 2;
  float s0 = wsc[m0], s1 = wsc[m1];
  f4 a = __builtin_nontemporal_load(out16 + (size_t)m0 * NN * 8 + r8);
  f4 b = __builtin_nontemporal_load(out16 + (size_t)m1 * NN * 8 + r8);
  float av[8], bv[8];
  unpack8(a, av);
  unpack8(b, bv);
  float4 o0, o1;
  o0.x = s0 * av[0] + s1 * bv[0];
  o0.y = s0 * av[1] + s1 * bv[1];
  o0.z = s0 * av[2] + s1 * bv[2];
  o0.w = s0 * av[3] + s1 * bv[3];
  o1.x = s0 * av[4] + s1 * bv[4];
  o1.y = s0 * av[5] + s1 * bv[5];
  o1.z = s0 * av[6] + s1 * bv[6];
  o1.w = s0 * av[7] + s1 * bv[7];
  ((float4*)out)[i8 * 2] = o0;
  ((float4*)out)[i8 * 2 + 1] = o1;
}

// ---------------------------------------------------------------------------
extern "C" void kernel_launch(void* const* d_in, const int* in_sizes, int n_in,
                              void* d_out, int out_size, void* d_ws,
                              size_t ws_size, hipStream_t stream) {
  const float* x_a = (const float*)d_in[0];
  const float* x_p = (const float*)d_in[1];
  const int* ei0 = (const int*)d_in[2];   // a->p
  const int* ei1 = (const int*)d_in[3];   // p->a
  const int* ei2 = (const int*)d_in[4];   // a->a
  const int* ei3 = (const int*)d_in[5];   // p->p
  const float* Wfa = (const float*)d_in[6];
  const float* bfa = (const float*)d_in[7];
  const float* Wfp = (const float*)d_in[8];
  const float* bfp = (const float*)d_in[9];
  const float* gWs = (const float*)d_in[10];
  const float* gWd = (const float*)d_in[11];
  const float* gas = (const float*)d_in[12];
  const float* gad = (const float*)d_in[13];
  const float* gb = (const float*)d_in[14];
  const float* Wk = (const float*)d_in[15];
  const float* bk = (const float*)d_in[16];
  const float* q = (const float*)d_in[17];
  float* out = (float*)d_out;
  (void)in_sizes; (void)n_in; (void)out_size; (void)ws_size;

  float* ws = (float*)d_ws;
  f4* h16 = (f4*)ws;                                 // 2*N rows x 16B
  f4* out16 = (f4*)(ws + (size_t)2 * NN * 4);        // 4*N rows x 128B (fp16)
  float* Vs = ws + (size_t)2 * NN * 4 + (size_t)4 * NN * 32;  // 256
  float* Vd = Vs + 256;                              // 256
  float* key = Vd + 256;                             // 256
  float* wsc = key + 256;                            // 8 (4 used)
  int* counts = (int*)(wsc + 8);                     // 4*N
  int* rowptr = counts + (size_t)4 * NN;             // 4*N
  int* gcur = rowptr + (size_t)4 * NN;               // 4*NBUK (pad 1024)
  int* edge_src = gcur + 1024;                       // 4*NBUK*CAP ints

  hipMemsetAsync(gcur, 0, 1024 * sizeof(int), stream);
  hipMemsetAsync(key, 0, 256 * sizeof(float), stream);

  fc_bin_kernel<<<FUSEGRID, 256, FUSESMEM, stream>>>(
      x_a, x_p, Wfa, bfa, Wfp, bfp, h16,
      ei0, ei1, ei2, ei3, gcur, edge_src,
      gWs, gas, gWd, gad, Vs, Vd);
  csr_kernel<<<dim3(NBUK, 4), 256, 0, stream>>>(gcur, edge_src, counts, rowptr);
  gat_pull<<<1568, 256, 0, stream>>>(h16, rowptr, counts, edge_src,
                                     gWs, Vs, Vd, gb, out16);
  semantic_key<<<dim3(SKB3, 4), 256, 0, stream>>>(out16, Wk, bk, key);
  scores_k<<<1, 64, 0, stream>>>(key, q, wsc);
  combine_kernel<<<(2 * NN * 8 + 255) / 256, 256, 0, stream>>>(out16, wsc, out);
}

// Round 30
// 275.138 us; speedup vs baseline: 1.0478x; 1.0478x over previous
//
#include <hip/hip_runtime.h>
#include <hip/hip_fp16.h>
#include <math.h>

#define NN 100000
#define EE 1600000
#define IND 256
#define SLOPE 0.2f

#define BUKBITS 9
#define BUKSZ 512            // nodes per bucket
#define NBUK 196             // ceil(NN/512)
#define CAP 8960             // bucket capacity: mean 8192 + 8*sigma(90)
#define CHUNK 4096           // edges per bin block
#define BINBLK 391           // ceil(EE/CHUNK)
#define NODEBLK 391          // ceil(NN/256)
#define SKB3 256             // semantic_key v7 blocks per m-slice
#define SKTILES 6250         // NN/16 exactly
#define FCB (2 * NODEBLK)    // 782 fc-role blocks
#define FUSEGRID (FCB + 4 * BINBLK + 1)   // 2347: fc + bin + prep_V roles
#define FUSESMEM 22832       // bin role's LDS need (max of roles)

typedef float f4 __attribute__((ext_vector_type(4)));     // native vec for nt builtins
typedef _Float16 h2 __attribute__((ext_vector_type(2)));  // packed fp16 pair
typedef _Float16 h8 __attribute__((ext_vector_type(8)));  // MFMA A/B fragment
typedef float fx4 __attribute__((ext_vector_type(4)));    // MFMA C/D fragment

// ---------------------------------------------------------------------------
// fp16 row unpack: 16B raw -> 8 floats
// ---------------------------------------------------------------------------
__device__ __forceinline__ void unpack8(const f4& raw, float* hs) {
  union { f4 v; __half2 p[4]; } u;
  u.v = raw;
#pragma unroll
  for (int j = 0; j < 4; ++j) {
    float2 f = __half22float2(u.p[j]);
    hs[2 * j] = f.x;
    hs[2 * j + 1] = f.y;
  }
}

// ---------------------------------------------------------------------------
// FUSED fc + bin + prep_V (r28 contiguous role mapping — best measured).
// r29's interleaved mapping was null/regressive: the fused stage is bound by
// memory-system interference (162MB mixed-pattern @ ~1.6TB/s ~= 128us), not
// by role co-residency. Contiguous ranges restored:
//   blocks [0, FCB)            : fc role (r18 code, frozen)
//   blocks [FCB, FCB+4*BINBLK) : bin role
//   block  FUSEGRID-1          : prep_V role (256-thread variant)
// ---------------------------------------------------------------------------
__global__ __launch_bounds__(256) void fc_bin_kernel(
    const float* __restrict__ xa, const float* __restrict__ xp,
    const float* __restrict__ Wa, const float* __restrict__ ba,
    const float* __restrict__ Wp, const float* __restrict__ bp,
    f4* __restrict__ h16,
    const int* __restrict__ e0, const int* __restrict__ e1,
    const int* __restrict__ e2, const int* __restrict__ e3,
    int* __restrict__ gcur, int* __restrict__ edge_src,
    const float* __restrict__ gWs, const float* __restrict__ gas,
    const float* __restrict__ gWd, const float* __restrict__ gad,
    float* __restrict__ Vs, float* __restrict__ Vd) {
  extern __shared__ char smem[];
  int t = threadIdx.x;
  if (blockIdx.x < FCB) {
    // ======================= fc role (r18, frozen) =======================
    float* sW = (float*)smem;          // 8 KB
    float* sB = sW + IND * 8;          // 32 B
    int bid = blockIdx.x;
    int type = bid >= NODEBLK;
    int lrow = (type ? bid - NODEBLK : bid) * 256 + t;
    const float* W = type ? Wp : Wa;
    const float* bb = type ? bp : ba;
    for (int i = t; i < IND * 8; i += 256) sW[i] = W[i];
    if (t < 8) sB[t] = bb[t];
    __syncthreads();
    if (lrow >= NN) return;
    const float* x = (type ? xp : xa) + (size_t)lrow * IND;
    float acc[8];
#pragma unroll
    for (int c = 0; c < 8; ++c) acc[c] = sB[c];
#pragma unroll 4
    for (int k4 = 0; k4 < IND / 4; ++k4) {
      float4 xv = ((const float4*)x)[k4];
      float xk[4] = {xv.x, xv.y, xv.z, xv.w};
#pragma unroll
      for (int kk = 0; kk < 4; ++kk) {
        const float* wr = &sW[(k4 * 4 + kk) * 8];
#pragma unroll
        for (int c = 0; c < 8; ++c) acc[c] = fmaf(xk[kk], wr[c], acc[c]);
      }
    }
    union { f4 v; __half2 p[4]; } u;
#pragma unroll
    for (int c = 0; c < 4; ++c)
      u.p[c] = __floats2half2_rn(acc[2 * c], acc[2 * c + 1]);
    h16[(size_t)type * NN + lrow] = u.v;
  } else if (blockIdx.x < FCB + 4 * BINBLK) {
    // ============================ bin role ==============================
    int b = blockIdx.x - FCB;
    int et = b / BINBLK;
    int chunk = b - et * BINBLK;
    int* s_pack = (int*)smem;                               // 16 KB
    unsigned char* s_buk = (unsigned char*)(s_pack + CHUNK); // 4 KB
    int* s_hist = (int*)(s_buk + CHUNK);                    // 784 B
    int* s_base = s_hist + NBUK;                            // 784 B
    int* s_cur = s_base + NBUK;                             // 784 B
    const int* ei = et == 0 ? e0 : et == 1 ? e1 : et == 2 ? e2 : e3;
    for (int bb = t; bb < NBUK; bb += 256) { s_hist[bb] = 0; s_cur[bb] = 0; }
    __syncthreads();
    int base = chunk * CHUNK;
#pragma unroll
    for (int r = 0; r < CHUNK / 256; ++r) {
      int i = r * 256 + t;
      int e = base + i;
      int bk = 255;
      if (e < EE) {
        int s = __builtin_nontemporal_load(ei + e);
        int d = __builtin_nontemporal_load(ei + EE + e);
        s_pack[i] = s | ((d & (BUKSZ - 1)) << 17);
        bk = d >> BUKBITS;
        atomicAdd(&s_hist[bk], 1);
      }
      s_buk[i] = (unsigned char)bk;
    }
    __syncthreads();
    for (int bb = t; bb < NBUK; bb += 256)
      s_base[bb] = atomicAdd(&gcur[et * NBUK + bb], s_hist[bb]);
    __syncthreads();
#pragma unroll
    for (int r = 0; r < CHUNK / 256; ++r) {
      int i = r * 256 + t;
      int bk = s_buk[i];
      if (bk != 255) {
        int pos = s_base[bk] + atomicAdd(&s_cur[bk], 1);
        if (pos < CAP)  // statistically impossible overflow guard
          edge_src[(size_t)(et * NBUK + bk) * CAP + pos] = s_pack[i];
      }
    }
  } else {
    // =========================== prep_V role ============================
    int et = t >> 6, k = (t >> 3) & 7, hh = t & 7;
    float accS = 0.f, accD = 0.f;
#pragma unroll
    for (int c = 0; c < 8; ++c) {
      accS += gWs[et * 512 + k * 64 + hh * 8 + c] * gas[et * 64 + hh * 8 + c];
      accD += gWd[et * 512 + k * 64 + hh * 8 + c] * gad[et * 64 + hh * 8 + c];
    }
    Vs[et * 64 + k * 8 + hh] = accS;
    Vd[et * 64 + k * 8 + hh] = accD;
  }
}

// ---------------------------------------------------------------------------
// Phase 2: per-bucket CSR (256 threads).
// ---------------------------------------------------------------------------
__global__ __launch_bounds__(256) void csr_kernel(
    const int* __restrict__ gcur, int* __restrict__ edge_src,
    int* __restrict__ counts, int* __restrict__ rowptr) {
  __shared__ int s_data[CAP];
  __shared__ int s_hist[BUKSZ], s_off[BUKSZ], s_part[256];
  int buk = blockIdx.x, et = blockIdx.y, t = threadIdx.x;
  int bsz = gcur[et * NBUK + buk];
  if (bsz > CAP) bsz = CAP;
  int ebase = (et * NBUK + buk) * CAP;
  for (int j = t; j < BUKSZ; j += 256) s_hist[j] = 0;
  __syncthreads();
  for (int i = t; i < bsz; i += 256) {
    int v = __builtin_nontemporal_load(edge_src + ebase + i);
    s_data[i] = v;
    atomicAdd(&s_hist[v >> 17], 1);
  }
  __syncthreads();
  int b2 = t * 2;
  int a0 = s_hist[b2], a1 = s_hist[b2 + 1];
  int tot = a0 + a1;
  s_part[t] = tot;
  __syncthreads();
#pragma unroll
  for (int off = 1; off < 256; off <<= 1) {
    int v = (t >= off) ? s_part[t - off] : 0;
    __syncthreads();
    s_part[t] += v;
    __syncthreads();
  }
  int ex = s_part[t] - tot;
  s_off[b2] = ex;
  s_off[b2 + 1] = ex + a0;
  __syncthreads();
  for (int j = t; j < BUKSZ; j += 256) {
    int node = buk * BUKSZ + j;
    if (node < NN) {
      counts[(size_t)et * NN + node] = s_hist[j];
      rowptr[(size_t)et * NN + node] = ebase + s_off[j];
    }
  }
  __syncthreads();
  for (int i = t; i < bsz; i += 256) {
    int v = s_data[i];
    int pos = atomicAdd(&s_off[v >> 17], 1);
    edge_src[ebase + pos] = v & 0x1FFFF;
  }
}

// ---------------------------------------------------------------------------
// GAT pull edge step (fp16 src row).
// ---------------------------------------------------------------------------
__device__ __forceinline__ void gat_edge16(
    const f4& raw, const float* __restrict__ Vse,
    const float ad[8], float g[64], float z[8]) {
  float hs[8];
  unpack8(raw, hs);
#pragma unroll
  for (int hh = 0; hh < 8; ++hh) {
    float e = ad[hh];
#pragma unroll
    for (int k = 0; k < 8; ++k) e = fmaf(hs[k], Vse[k * 8 + hh], e);
    e = e > 0.f ? e : SLOPE * e;
    float w = __expf(e);
    z[hh] += w;
#pragma unroll
    for (int k = 0; k < 8; ++k) g[hh * 8 + k] = fmaf(w, hs[k], g[hh * 8 + k]);
  }
}

// ---------------------------------------------------------------------------
// GAT pull: thread-per-node, fp16 h (1 gather/edge), 4-edge batches,
// fp16 out_et epilogue. Validated L2-request-rate floor (~95us).
// ---------------------------------------------------------------------------
__global__ __launch_bounds__(256) void gat_pull(
    const f4* __restrict__ h16,
    const int* __restrict__ rowptr, const int* __restrict__ counts,
    const int* __restrict__ edge_src,
    const float* __restrict__ Wsrc_all, const float* __restrict__ Vs,
    const float* __restrict__ Vd,
    const float* __restrict__ bias_all, f4* __restrict__ out16) {
  int b = blockIdx.x;
  int xcd = b & 7;
  int g_ = xcd >> 2;                      // src type this XCD owns
  int sid = (b >> 3) * 4 + (xcd & 3);     // 0..783
  if (sid >= 2 * NODEBLK) return;
  int et = (sid < NODEBLK) ? g_ : g_ + 2; // a:{0,2}  p:{1,3}
  int nb = (sid < NODEBLK) ? sid : sid - NODEBLK;
  int n = nb * 256 + threadIdx.x;
  if (n >= NN) return;
  int st = et & 1;                           // src type: 0=a,1=p
  int dt = (et & 1) ^ (et < 2 ? 1 : 0);      // dst type
  const f4* hsrc = h16 + (size_t)st * NN;
  const f4* hdst = h16 + (size_t)dt * NN;
  const float* Ws = Wsrc_all + et * 512;
  const float* Vse = Vs + et * 64;
  const float* Vde = Vd + et * 64;
  const float* bs = bias_all + et * 64;

  float hd[8];
  unpack8(hdst[n], hd);
  float ad[8];
#pragma unroll
  for (int hh = 0; hh < 8; ++hh) {
    float acc = 0.f;
#pragma unroll
    for (int k = 0; k < 8; ++k) acc = fmaf(hd[k], Vde[k * 8 + hh], acc);
    ad[hh] = acc;
  }
  float g[64];
  float z[8];
#pragma unroll
  for (int i = 0; i < 64; ++i) g[i] = 0.f;
#pragma unroll
  for (int hh = 0; hh < 8; ++hh) z[hh] = 0.f;

  int start = rowptr[(size_t)et * NN + n];
  int deg = counts[(size_t)et * NN + n];
  const int* es = edge_src + start;
  int i = 0;
#pragma unroll 1
  for (; i + 4 <= deg; i += 4) {
    int s0 = __builtin_nontemporal_load(es + i);
    int s1 = __builtin_nontemporal_load(es + i + 1);
    int s2 = __builtin_nontemporal_load(es + i + 2);
    int s3 = __builtin_nontemporal_load(es + i + 3);
    f4 r0 = hsrc[s0];
    f4 r1 = hsrc[s1];
    f4 r2 = hsrc[s2];
    f4 r3 = hsrc[s3];
    gat_edge16(r0, Vse, ad, g, z);
    gat_edge16(r1, Vse, ad, g, z);
    gat_edge16(r2, Vse, ad, g, z);
    gat_edge16(r3, Vse, ad, g, z);
  }
#pragma unroll 1
  for (; i < deg; ++i) {
    int s = __builtin_nontemporal_load(es + i);
    f4 r = hsrc[s];
    gat_edge16(r, Vse, ad, g, z);
  }

  f4* op = out16 + ((size_t)et * NN + n) * 8;   // 8 f4 chunks = 64 halves
#pragma unroll
  for (int hh = 0; hh < 8; ++hh) {
    float rz = 1.f / (z[hh] + 1e-16f);
    float o[8];
#pragma unroll
    for (int c = 0; c < 8; ++c) {
      float acc = 0.f;
#pragma unroll
      for (int k = 0; k < 8; ++k)
        acc = fmaf(g[hh * 8 + k], Ws[k * 64 + hh * 8 + c], acc);
      o[c] = acc * rz + bs[hh * 8 + c];
    }
    union { f4 v; __half2 p[4]; } u;
#pragma unroll
    for (int c = 0; c < 4; ++c)
      u.p[c] = __floats2half2_rn(o[2 * c], o[2 * c + 1]);
    op[hh] = u.v;
  }
}

// ---------------------------------------------------------------------------
// Semantic attention keys (v7, MFMA) — r24 verified.
// ---------------------------------------------------------------------------
__global__ __launch_bounds__(256) void semantic_key(
    const f4* __restrict__ out16, const float* __restrict__ Wk,
    const float* __restrict__ bk, float* __restrict__ key) {
  __shared__ float s_red[4][64];
  int m = blockIdx.y;
  int t = threadIdx.x;
  int lane = t & 63;
  int w = t >> 6;
  int kg = lane >> 4;      // k-group 0..3
  int col = lane & 15;
  h8 bfrag[2][4];
#pragma unroll
  for (int ks = 0; ks < 2; ++ks)
#pragma unroll
    for (int jt = 0; jt < 4; ++jt) {
      h8 bf;
#pragma unroll
      for (int i = 0; i < 8; ++i)
        bf[i] = (_Float16)Wk[(ks * 32 + kg * 8 + i) * 64 + jt * 16 + col];
      bfrag[ks][jt] = bf;
    }
  float bkv[4];
#pragma unroll
  for (int jt = 0; jt < 4; ++jt) bkv[jt] = bk[jt * 16 + col];
  float kacc[4] = {0.f, 0.f, 0.f, 0.f};
  const f4* base = out16 + (size_t)m * NN * 8;
  int gw = blockIdx.x * 4 + w;            // 0..1023
#pragma unroll 1
  for (int tile = gw; tile < SKTILES; tile += SKB3 * 4) {
    union { f4 v; h8 h; } a0u, a1u;
    const f4* rowp = base + (size_t)(tile * 16 + col) * 8;
    a0u.v = rowp[kg];
    a1u.v = rowp[4 + kg];
#pragma unroll
    for (int jt = 0; jt < 4; ++jt) {
      fx4 d = {0.f, 0.f, 0.f, 0.f};
      d = __builtin_amdgcn_mfma_f32_16x16x32_f16(a0u.h, bfrag[0][jt], d, 0, 0, 0);
      d = __builtin_amdgcn_mfma_f32_16x16x32_f16(a1u.h, bfrag[1][jt], d, 0, 0, 0);
#pragma unroll
      for (int r = 0; r < 4; ++r) {
        float x = d[r] + bkv[jt];
        kacc[jt] += 1.f - 2.f / (__expf(2.f * x) + 1.f);  // tanh
      }
    }
  }
#pragma unroll
  for (int jt = 0; jt < 4; ++jt) {
    kacc[jt] += __shfl_xor(kacc[jt], 16, 64);
    kacc[jt] += __shfl_xor(kacc[jt], 32, 64);
  }
  if (lane < 16) {
#pragma unroll
    for (int jt = 0; jt < 4; ++jt) s_red[w][jt * 16 + col] = kacc[jt];
  }
  __syncthreads();
  if (t < 64) {
    float v = s_red[0][t] + s_red[1][t] + s_red[2][t] + s_red[3][t];
    atomicAdd(&key[m * 64 + t], v);
  }
}

// ---------------------------------------------------------------------------
// Scores: softmax over each node-type's pair of edge types.
// ---------------------------------------------------------------------------
__global__ __launch_bounds__(64) void scores_k(
    const float* __restrict__ key, const float* __restrict__ q,
    float* __restrict__ wsc) {
  int l = threadIdx.x;
  float qv = q[l];
  float d[4];
#pragma unroll
  for (int m = 0; m < 4; ++m) {
    float p = qv * key[m * 64 + l];
#pragma unroll
    for (int off = 32; off; off >>= 1) p += __shfl_xor(p, off, 64);
    d[m] = p * (1.0f / NN);  // mean over nodes
  }
  if (l == 0) {
    {
      float mx = fmaxf(d[1], d[2]);
      float e1 = __expf(d[1] - mx), e2 = __expf(d[2] - mx);
      float inv = 1.f / (e1 + e2);
      wsc[1] = e1 * inv;
      wsc[2] = e2 * inv;
    }
    {
      float mx = fmaxf(d[0], d[3]);
      float e0 = __expf(d[0] - mx), e3 = __expf(d[3] - mx);
      float inv = 1.f / (e0 + e3);
      wsc[0] = e0 * inv;
      wsc[3] = e3 * inv;
    }
  }
}

// ---------------------------------------------------------------------------
// Combine (fp16 out_et): thread handles 8 outputs (16B fp16 per et half).
// ---------------------------------------------------------------------------
__global__ __launch_bounds__(256) void combine_kernel(
    const f4* __restrict__ out16, const float* __restrict__ wsc,
    float* __restrict__ out) {
  size_t i8 = (size_t)blockIdx.x * 256 + threadIdx.x;  // 8-float chunk over [2][N][8]
  if (i8 >= (size_t)2 * NN * 8) return;
  int type = i8 >= (size_t)NN * 8;
  size_t r8 = type ? i8 - (size_t)NN * 8 : i8;
  int m0 = type ? 0 : 1;
  int m1 = type ? 3 : 2;
  float s0 = wsc[m0], s1 = wsc[m1];
  f4 a = __builtin_nontemporal_load(out16 + (size_t)m0 * NN * 8 + r8);
  f4 b = __builtin_nontemporal_load(out16 + (size_t)m1 * NN * 8 + r8);
  float av[8], bv[8];
  unpack8(a, av);
  unpack8(b, bv);
  float4 o0, o1;
  o0.x = s0 * av[0] + s1 * bv[0];
  o0.y = s0 * av[1] + s1 * bv[1];
  o0.z = s0 * av[2] + s1 * bv[2];
  o0.w = s0 * av[3] + s1 * bv[3];
  o1.x = s0 * av[4] + s1 * bv[4];
  o1.y = s0 * av[5] + s1 * bv[5];
  o1.z = s0 * av[6] + s1 * bv[6];
  o1.w = s0 * av[7] + s1 * bv[7];
  ((float4*)out)[i8 * 2] = o0;
  ((float4*)out)[i8 * 2 + 1] = o1;
}

// ---------------------------------------------------------------------------
extern "C" void kernel_launch(void* const* d_in, const int* in_sizes, int n_in,
                              void* d_out, int out_size, void* d_ws,
                              size_t ws_size, hipStream_t stream) {
  const float* x_a = (const float*)d_in[0];
  const float* x_p = (const float*)d_in[1];
  const int* ei0 = (const int*)d_in[2];   // a->p
  const int* ei1 = (const int*)d_in[3];   // p->a
  const int* ei2 = (const int*)d_in[4];   // a->a
  const int* ei3 = (const int*)d_in[5];   // p->p
  const float* Wfa = (const float*)d_in[6];
  const float* bfa = (const float*)d_in[7];
  const float* Wfp = (const float*)d_in[8];
  const float* bfp = (const float*)d_in[9];
  const float* gWs = (const float*)d_in[10];
  const float* gWd = (const float*)d_in[11];
  const float* gas = (const float*)d_in[12];
  const float* gad = (const float*)d_in[13];
  const float* gb = (const float*)d_in[14];
  const float* Wk = (const float*)d_in[15];
  const float* bk = (const float*)d_in[16];
  const float* q = (const float*)d_in[17];
  float* out = (float*)d_out;
  (void)in_sizes; (void)n_in; (void)out_size; (void)ws_size;

  float* ws = (float*)d_ws;
  f4* h16 = (f4*)ws;                                 // 2*N rows x 16B
  f4* out16 = (f4*)(ws + (size_t)2 * NN * 4);        // 4*N rows x 128B (fp16)
  float* Vs = ws + (size_t)2 * NN * 4 + (size_t)4 * NN * 32;  // 256
  float* Vd = Vs + 256;                              // 256
  float* key = Vd + 256;                             // 256
  float* wsc = key + 256;                            // 8 (4 used)
  int* counts = (int*)(wsc + 8);                     // 4*N
  int* rowptr = counts + (size_t)4 * NN;             // 4*N
  int* gcur = rowptr + (size_t)4 * NN;               // 4*NBUK (pad 1024)
  int* edge_src = gcur + 1024;                       // 4*NBUK*CAP ints

  hipMemsetAsync(gcur, 0, 1024 * sizeof(int), stream);
  hipMemsetAsync(key, 0, 256 * sizeof(float), stream);

  fc_bin_kernel<<<FUSEGRID, 256, FUSESMEM, stream>>>(
      x_a, x_p, Wfa, bfa, Wfp, bfp, h16,
      ei0, ei1, ei2, ei3, gcur, edge_src,
      gWs, gas, gWd, gad, Vs, Vd);
  csr_kernel<<<dim3(NBUK, 4), 256, 0, stream>>>(gcur, edge_src, counts, rowptr);
  gat_pull<<<1568, 256, 0, stream>>>(h16, rowptr, counts, edge_src,
                                     gWs, Vs, Vd, gb, out16);
  semantic_key<<<dim3(SKB3, 4), 256, 0, stream>>>(out16, Wk, bk, key);
  scores_k<<<1, 64, 0, stream>>>(key, q, wsc);
  combine_kernel<<<(2 * NN * 8 + 255) / 256, 256, 0, stream>>>(out16, wsc, out);
}